// Round 1
// baseline (3838.383 us; speedup 1.0000x reference)
//
#include <hip/hip_runtime.h>
#include <math.h>

#define TILE_E 16
#define UCH 8
#define NINS 11
#define IND 288
#define SHD 9
#define W2N 11264

__device__ const int c_L1[NINS] = {0,0,0,1,1,1,1,2,2,2,2};
__device__ const int c_L2[NINS] = {0,1,2,0,1,1,2,0,1,2,2};
__device__ const int c_L3[NINS] = {0,1,2,1,0,2,1,2,1,0,2};
__device__ const int c_W3OFF[NINS] = {0,1,10,35,44,53,98,143,168,213,238};

__device__ __forceinline__ int xoff(int l){ return l==0?0:(l==1?32:128); }
__device__ __forceinline__ int shoff(int l){ return l==0?0:(l==1?1:4); }

// ---------------- Wigner 3j on device (exact port of reference) ----------------
__device__ double dfac(int n){ double r=1.0; for(int i=2;i<=n;++i) r*=(double)i; return r; }

__device__ void su2_cg(int j1,int j2,int j3,double* C){
  int d1=2*j1+1,d2=2*j2+1,d3=2*j3+1;
  for(int i=0;i<d1*d2*d3;++i) C[i]=0.0;
  for(int m1=-j1;m1<=j1;++m1)
  for(int m2=-j2;m2<=j2;++m2){
    int m3=m1+m2;
    if(m3<-j3||m3>j3) continue;
    int vmin=-j1+j2+m3; if(-j1+m1>vmin)vmin=-j1+m1; if(0>vmin)vmin=0;
    int vmax=j2+j3+m1; if(j3-j1+j2<vmax)vmax=j3-j1+j2; if(j3+m3<vmax)vmax=j3+m3;
    double c=sqrt((double)(2*j3+1)*dfac(j3+j1-j2)*dfac(j3-j1+j2)*dfac(j1+j2-j3)
      *dfac(j3+m3)*dfac(j3-m3)
      /(dfac(j1+j2+j3+1)*dfac(j1-m1)*dfac(j1+m1)*dfac(j2-m2)*dfac(j2+m2)));
    double s=0.0;
    for(int v=vmin;v<=vmax;++v){
      double term=dfac(j2+j3+m1-v)*dfac(j1-m1+v)
        /(dfac(v)*dfac(j3-j1+j2-v)*dfac(j3+m3-v)*dfac(v+j1-j2-m3));
      s += (((v+j2+m2)&1)?-1.0:1.0)*term;
    }
    C[((m1+j1)*d2+(m2+j2))*d3+(m3+j3)]=c*s;
  }
}

__device__ void qmat(int l,double* qr,double* qi){
  int d=2*l+1;
  for(int i=0;i<d*d;++i){qr[i]=0.0;qi[i]=0.0;}
  const double s=0.70710678118654752440;
  for(int m=-l;m<0;++m){
    qr[(l+m)*d+(l-m)]=s;       // q[l+m, l+|m|] = 2^-0.5
    qi[(l+m)*d+(l+m)]=-s;      // q[l+m, l-|m|] = -i*2^-0.5
  }
  qr[l*d+l]=1.0;
  for(int m=1;m<=l;++m){
    double sg=(m&1)?-1.0:1.0;
    qr[(l+m)*d+(l+m)]=sg*s;
    qi[(l+m)*d+(l-m)]=sg*s;
  }
  // multiply by (-i)^l
  if(l==1){ for(int i=0;i<d*d;++i){ double a=qr[i],b=qi[i]; qr[i]=b; qi[i]=-a; } }
  else if(l==2){ for(int i=0;i<d*d;++i){ qr[i]=-qr[i]; qi[i]=-qi[i]; } }
}

__global__ void w3j_kernel(float* w3j){
  int i=threadIdx.x;
  if(i>=NINS) return;
  int l1=c_L1[i],l2=c_L2[i],l3=c_L3[i];
  int d1=2*l1+1,d2=2*l2+1,d3=2*l3+1;
  double C[125]; su2_cg(l1,l2,l3,C);
  double q1r[25],q1i[25],q2r[25],q2i[25],q3r[25],q3i[25];
  qmat(l1,q1r,q1i); qmat(l2,q2r,q2i); qmat(l3,q3r,q3i);
  double R[125];
  double n2=0.0;
  for(int j=0;j<d1;++j)for(int l=0;l<d2;++l)for(int m=0;m<d3;++m){
    double sr=0.0;
    for(int a=0;a<d1;++a)for(int b=0;b<d2;++b)for(int n=0;n<d3;++n){
      double cv=C[(a*d2+b)*d3+n];
      if(cv==0.0) continue;
      double xr=q1r[a*d1+j],xi=q1i[a*d1+j];
      double yr=q2r[b*d2+l],yi=q2i[b*d2+l];
      double zr=q3r[n*d3+m],zi=-q3i[n*d3+m];   // conj(Q3[n][m])
      double pr=xr*yr-xi*yi, pi=xr*yi+xi*yr;
      double rr=pr*zr-pi*zi;                   // real part of product
      sr+=rr*cv;
    }
    R[(j*d2+l)*d3+m]=sr;
    n2+=sr*sr;
  }
  double inv=1.0/sqrt(n2);
  float* dst=w3j+c_W3OFF[i];
  for(int idx=0;idx<d1*d2*d3;++idx) dst[idx]=(float)(R[idx]*inv);
}

// ---------------- self connection: out[n] = o3.Linear(x[n]) ----------------
__global__ __launch_bounds__(256) void sc_kernel(const float* __restrict__ x,
  const float* __restrict__ W0, const float* __restrict__ W1s, const float* __restrict__ W2s,
  float* __restrict__ out, int n_nodes)
{
  int n=blockIdx.x;
  if(n>=n_nodes) return;
  const float inv=0.17677669529663689f;  // 1/sqrt(32)
  for(int o=threadIdx.x; o<IND; o+=blockDim.x){
    const float* W; int w,k,d,xo;
    if(o<32){W=W0; w=o; k=0; d=1; xo=0;}
    else if(o<128){int r=o-32; W=W1s; d=3; w=r/3; k=r-w*3; xo=32;}
    else {int r=o-128; W=W2s; d=5; w=r/5; k=r-w*5; xo=128;}
    float s=0.f;
    const float* xr=x+(size_t)n*IND+xo+k;
    for(int u=0;u<32;++u) s += xr[u*d]*W[u*32+w];
    out[(size_t)n*IND+o]=s*inv;
  }
}

// ---------------- fused weight-NN + tensor product + scatter ----------------
__global__ __launch_bounds__(256) void tp_kernel(
    const float* __restrict__ x, const int* __restrict__ eidx,
    const float* __restrict__ sh, const float* __restrict__ radial,
    const float* __restrict__ W1, const float* __restrict__ W2,
    const float* __restrict__ w3j, float* __restrict__ out,
    int E, float pwc0, float pwc1, float pwc2, float silu_cst)
{
  __shared__ float hs_t[64*TILE_E];       // [c][e] transposed
  __shared__ float shl[TILE_E][SHD];
  __shared__ float shw[TILE_E][25];       // per-ins: sum_j w3j[i,j,k]*sh[j]
  __shared__ float ybuf[TILE_E][160];     // per-ins: y[u*d3+k]
  __shared__ float wi[TILE_E][UCH][32];
  __shared__ float msg[TILE_E][IND];
  __shared__ int srcs[TILE_E];
  __shared__ int dsts[TILE_E];

  const int t=threadIdx.x;
  const int e0=blockIdx.x*TILE_E;

  if(t<TILE_E){
    int eg=e0+t;
    srcs[t]= (eg<E)? eidx[eg] : -1;
    dsts[t]= (eg<E)? eidx[E+eg] : -1;
  }
  // h = SILU_CST * silu(radial @ W1 / 8), stored transposed [c][e]
  for(int idx=t; idx<TILE_E*64; idx+=256){
    int e=idx>>6, c=idx&63;
    int eg=e0+e;
    float hv=0.f;
    if(eg<E){
      const float* rr=radial+(size_t)eg*64;
      float acc=0.f;
      #pragma unroll 8
      for(int r=0;r<64;++r) acc += rr[r]*W1[r*64+c];
      acc*=0.125f;
      hv=silu_cst*acc/(1.f+expf(-acc));
    }
    hs_t[c*TILE_E+e]=hv;
  }
  for(int idx=t; idx<TILE_E*SHD; idx+=256){
    int e=idx/SHD, j=idx-e*SHD;
    int eg=e0+e;
    shl[e][j]= (eg<E)? sh[(size_t)eg*SHD+j] : 0.f;
  }
  for(int idx=t; idx<TILE_E*IND; idx+=256) msg[idx/IND][idx-(idx/IND)*IND]=0.f;
  __syncthreads();

  for(int ins=0; ins<NINS; ++ins){
    const int l1=c_L1[ins], l2=c_L2[ins], l3=c_L3[ins];
    const int d1=2*l1+1, d2=2*l2+1, d3=2*l3+1;
    const float* w3=w3j+c_W3OFF[ins];
    const int xo=xoff(l1), so=shoff(l2);
    // B1: shw[e][i*d3+k] = sum_j w3j[i,j,k]*sh[e,j]
    const int n1=TILE_E*d1*d3;
    for(int idx=t; idx<n1; idx+=256){
      int e=idx/(d1*d3), r=idx-e*(d1*d3);
      int i=r/d3, k=r-i*d3;
      float s=0.f;
      for(int j=0;j<d2;++j) s += w3[(i*d2+j)*d3+k]*shl[e][so+j];
      shw[e][r]=s;
    }
    __syncthreads();
    // B2: y[e][u*d3+k] = sum_i shw[e][i*d3+k] * x[src[e], xo+u*d1+i]
    const int n2=TILE_E*32*d3;
    for(int idx=t; idx<n2; idx+=256){
      int e=idx/(32*d3), r=idx-e*(32*d3);
      int u=r/d3, k=r-u*d3;
      float s=0.f;
      int srn=srcs[e];
      if(srn>=0){
        const float* xr=x+(size_t)srn*IND+xo+u*d1;
        for(int i=0;i<d1;++i) s += shw[e][i*d3+k]*xr[i];
      }
      ybuf[e][r]=s;
    }
    __syncthreads();
    const float pw=(l3==0)?pwc0:((l3==1)?pwc1:pwc2);
    const int oo=xoff(l3);
    const float* w2b=W2+ins*1024;
    for(int uc=0; uc<32/UCH; ++uc){
      { // wi[e][up][w] = sum_c h[e][c]*W2[c, ins*1024+(uc*8+up)*32+w]
        const int col=uc*256+t;           // up=t>>5, w=t&31
        const float* wp=w2b+col;
        float acc[TILE_E];
        #pragma unroll
        for(int e=0;e<TILE_E;++e) acc[e]=0.f;
        #pragma unroll 2
        for(int c=0;c<64;++c){
          float w2v=wp[(size_t)c*W2N];
          #pragma unroll
          for(int e=0;e<TILE_E;++e) acc[e] += hs_t[c*TILE_E+e]*w2v;
        }
        const int up=t>>5, w=t&31;
        #pragma unroll
        for(int e=0;e<TILE_E;++e) wi[e][up][w]=acc[e];
      }
      __syncthreads();
      // contract: msg[e][oo+w*d3+k] += pw * sum_up wi[e][up][w]*y[e][(uc*8+up)*d3+k]
      const int n3=TILE_E*32*d3;
      for(int idx=t; idx<n3; idx+=256){
        int e=idx/(32*d3), r=idx-e*(32*d3);
        int w=r/d3, k=r-w*d3;
        float s=0.f;
        #pragma unroll
        for(int up=0; up<UCH; ++up)
          s += wi[e][up][w]*ybuf[e][(uc*UCH+up)*d3+k];
        msg[e][oo+w*d3+k] += pw*s;
      }
      __syncthreads();
    }
  }
  // scatter to out[dst]
  for(int idx=t; idx<TILE_E*IND; idx+=256){
    int e=idx/IND, o=idx-e*IND;
    int d=dsts[e];
    if(d>=0) atomicAdd(&out[(size_t)d*IND+o], msg[e][o]);
  }
}

extern "C" void kernel_launch(void* const* d_in, const int* in_sizes, int n_in,
                              void* d_out, int out_size, void* d_ws, size_t ws_size,
                              hipStream_t stream){
  const float* x     =(const float*)d_in[0];
  const int*   eidx  =(const int*)  d_in[1];
  const float* sh    =(const float*)d_in[2];
  const float* radial=(const float*)d_in[3];
  const float* W1    =(const float*)d_in[4];
  const float* W2    =(const float*)d_in[5];
  const float* Wsc0  =(const float*)d_in[6];
  const float* Wsc1  =(const float*)d_in[7];
  const float* Wsc2  =(const float*)d_in[8];
  float* out=(float*)d_out;
  int n_nodes=in_sizes[0]/IND;
  int E=in_sizes[1]/2;

  float inv10=1.0f/sqrtf(10.0f);
  // PW[l]=sqrt((2l+1)/(n_paths*32)); fold in W2's 1/sqrt(64) and 1/sqrt(NUM_NEIGHBORS)
  float pwc0=sqrtf(1.0f/96.0f) *0.125f*inv10;
  float pwc1=sqrtf(3.0f/128.0f)*0.125f*inv10;
  float pwc2=sqrtf(5.0f/128.0f)*0.125f*inv10;
  float silu_cst=1.67682f;   // 1/sqrt(E[silu(N(0,1))^2]), analytic

  float* w3j=(float*)d_ws;   // 363 floats

  hipLaunchKernelGGL(w3j_kernel, dim3(1), dim3(64), 0, stream, w3j);
  hipLaunchKernelGGL(sc_kernel, dim3(n_nodes), dim3(256), 0, stream,
                     x, Wsc0, Wsc1, Wsc2, out, n_nodes);
  hipLaunchKernelGGL(tp_kernel, dim3((E+TILE_E-1)/TILE_E), dim3(256), 0, stream,
                     x, eidx, sh, radial, W1, W2, w3j, out, E,
                     pwc0, pwc1, pwc2, silu_cst);
}

// Round 2
// 1103.310 us; speedup vs baseline: 3.4790x; 3.4790x over previous
//
#include <hip/hip_runtime.h>
#include <math.h>

#define TILE_E 16
#define UCH 8
#define NINS 11
#define IND 288
#define SHD 9
#define W2N 11264

__device__ const int c_L1[NINS] = {0,0,0,1,1,1,1,2,2,2,2};
__device__ const int c_L2[NINS] = {0,1,2,0,1,1,2,0,1,2,2};
__device__ const int c_L3[NINS] = {0,1,2,1,0,2,1,2,1,0,2};
__device__ const int c_W3OFF[NINS] = {0,1,10,35,44,53,98,143,168,213,238};

__device__ __forceinline__ int xoff(int l){ return l==0?0:(l==1?32:128); }
__device__ __forceinline__ int shoff(int l){ return l==0?0:(l==1?1:4); }

// ---------------- Wigner 3j on device (exact port of reference, parallel) ----------------
__device__ double dfac(int n){ double r=1.0; for(int i=2;i<=n;++i) r*=(double)i; return r; }

__device__ void qmat_dev(int l,double* qr,double* qi){
  int d=2*l+1;
  for(int i=0;i<d*d;++i){qr[i]=0.0;qi[i]=0.0;}
  const double s=0.70710678118654752440;
  for(int m=-l;m<0;++m){
    qr[(l+m)*d+(l-m)]=s;       // q[l+m, l+|m|] = 2^-0.5
    qi[(l+m)*d+(l+m)]=-s;      // q[l+m, l-|m|] = -i*2^-0.5
  }
  qr[l*d+l]=1.0;
  for(int m=1;m<=l;++m){
    double sg=(m&1)?-1.0:1.0;
    qr[(l+m)*d+(l+m)]=sg*s;
    qi[(l+m)*d+(l-m)]=sg*s;
  }
  // multiply by (-i)^l
  if(l==1){ for(int i=0;i<d*d;++i){ double a=qr[i],b=qi[i]; qr[i]=b; qi[i]=-a; } }
  else if(l==2){ for(int i=0;i<d*d;++i){ qr[i]=-qr[i]; qi[i]=-qi[i]; } }
}

__global__ __launch_bounds__(128) void w3j_kernel(float* w3j){
  const int ins=blockIdx.x;
  const int l1=c_L1[ins],l2=c_L2[ins],l3=c_L3[ins];
  const int d1=2*l1+1,d2=2*l2+1,d3=2*l3+1;
  const int n=d1*d2*d3;
  const int t=threadIdx.x;

  __shared__ double C[125];
  __shared__ double R[125];
  __shared__ double q1r[25],q1i[25],q2r[25],q2i[25],q3r[25],q3i[25];
  __shared__ double inv;

  for(int i=t;i<125;i+=128) C[i]=0.0;
  if(t==0){
    qmat_dev(l1,q1r,q1i); qmat_dev(l2,q2r,q2i); qmat_dev(l3,q3r,q3i);
  }
  __syncthreads();

  // each thread p < d1*d2 computes one (m1,m2) slice of the CG tensor
  if(t<d1*d2){
    int m1=t/d2-l1, m2=t-(t/d2)*d2-l2;
    int m3=m1+m2;
    if(m3>=-l3 && m3<=l3){
      int vmin=-l1+l2+m3; if(-l1+m1>vmin)vmin=-l1+m1; if(0>vmin)vmin=0;
      int vmax=l2+l3+m1; if(l3-l1+l2<vmax)vmax=l3-l1+l2; if(l3+m3<vmax)vmax=l3+m3;
      double c=sqrt((double)(2*l3+1)*dfac(l3+l1-l2)*dfac(l3-l1+l2)*dfac(l1+l2-l3)
        *dfac(l3+m3)*dfac(l3-m3)
        /(dfac(l1+l2+l3+1)*dfac(l1-m1)*dfac(l1+m1)*dfac(l2-m2)*dfac(l2+m2)));
      double s=0.0;
      for(int v=vmin;v<=vmax;++v){
        double term=dfac(l2+l3+m1-v)*dfac(l1-m1+v)
          /(dfac(v)*dfac(l3-l1+l2-v)*dfac(l3+m3-v)*dfac(v+l1-l2-m3));
        s += (((v+l2+m2)&1)?-1.0:1.0)*term;
      }
      C[((m1+l1)*d2+(m2+l2))*d3+(m3+l3)]=c*s;
    }
  }
  __syncthreads();

  // each thread r < n computes one element of the real-basis tensor
  if(t<n){
    int j=t/(d2*d3);
    int rem=t-j*(d2*d3);
    int l=rem/d3, m=rem-l*d3;
    double sr=0.0;
    for(int a=0;a<d1;++a)for(int b=0;b<d2;++b)for(int nn=0;nn<d3;++nn){
      double cv=C[(a*d2+b)*d3+nn];
      if(cv==0.0) continue;
      double xr=q1r[a*d1+j],xi=q1i[a*d1+j];
      double yr=q2r[b*d2+l],yi=q2i[b*d2+l];
      double zr=q3r[nn*d3+m],zi=-q3i[nn*d3+m];   // conj(Q3[n][m])
      double pr=xr*yr-xi*yi, pi=xr*yi+xi*yr;
      sr += (pr*zr-pi*zi)*cv;
    }
    R[t]=sr;
  }
  __syncthreads();
  if(t==0){
    double n2=0.0;
    for(int i=0;i<n;++i) n2+=R[i]*R[i];
    inv=1.0/sqrt(n2);
  }
  __syncthreads();
  if(t<n) w3j[c_W3OFF[ins]+t]=(float)(R[t]*inv);
}

// ---------------- self connection: out[n] = o3.Linear(x[n]) ----------------
__global__ __launch_bounds__(256) void sc_kernel(const float* __restrict__ x,
  const float* __restrict__ W0, const float* __restrict__ W1s, const float* __restrict__ W2s,
  float* __restrict__ out, int n_nodes)
{
  int n=blockIdx.x;
  if(n>=n_nodes) return;
  const float inv=0.17677669529663689f;  // 1/sqrt(32)
  for(int o=threadIdx.x; o<IND; o+=blockDim.x){
    const float* W; int w,k,d,xo;
    if(o<32){W=W0; w=o; k=0; d=1; xo=0;}
    else if(o<128){int r=o-32; W=W1s; d=3; w=r/3; k=r-w*3; xo=32;}
    else {int r=o-128; W=W2s; d=5; w=r/5; k=r-w*5; xo=128;}
    float s=0.f;
    const float* xr=x+(size_t)n*IND+xo+k;
    for(int u=0;u<32;++u) s += xr[u*d]*W[u*32+w];
    out[(size_t)n*IND+o]=s*inv;
  }
}

// ---------------- fused weight-NN + tensor product + scatter ----------------
__global__ __launch_bounds__(256) void tp_kernel(
    const float* __restrict__ x, const int* __restrict__ eidx,
    const float* __restrict__ sh, const float* __restrict__ radial,
    const float* __restrict__ W1, const float* __restrict__ W2,
    const float* __restrict__ w3j, float* __restrict__ out,
    int E, float pwc0, float pwc1, float pwc2, float silu_cst)
{
  __shared__ float hs_t[64*TILE_E];       // [c][e] transposed, e contiguous
  __shared__ float shl[TILE_E][SHD];
  __shared__ float shw[TILE_E][25];       // per-ins: sum_j w3j[i,j,k]*sh[j]
  __shared__ float ybuf[TILE_E][160];     // per-ins: y[u*d3+k]
  __shared__ float wi[TILE_E][UCH][32];
  __shared__ float msg[TILE_E][IND];
  __shared__ int srcs[TILE_E];
  __shared__ int dsts[TILE_E];

  const int t=threadIdx.x;
  const int e0=blockIdx.x*TILE_E;

  if(t<TILE_E){
    int eg=e0+t;
    srcs[t]= (eg<E)? eidx[eg] : -1;
    dsts[t]= (eg<E)? eidx[E+eg] : -1;
  }
  // h = SILU_CST * silu(radial @ W1 / 8), stored transposed [c][e]
  for(int idx=t; idx<TILE_E*64; idx+=256){
    int e=idx>>6, c=idx&63;
    int eg=e0+e;
    float hv=0.f;
    if(eg<E){
      const float* rr=radial+(size_t)eg*64;
      float acc=0.f;
      #pragma unroll 8
      for(int r=0;r<64;++r) acc += rr[r]*W1[r*64+c];
      acc*=0.125f;
      hv=silu_cst*acc/(1.f+expf(-acc));
    }
    hs_t[c*TILE_E+e]=hv;
  }
  for(int idx=t; idx<TILE_E*SHD; idx+=256){
    int e=idx/SHD, j=idx-e*SHD;
    int eg=e0+e;
    shl[e][j]= (eg<E)? sh[(size_t)eg*SHD+j] : 0.f;
  }
  for(int idx=t; idx<TILE_E*IND; idx+=256) msg[idx/IND][idx-(idx/IND)*IND]=0.f;
  __syncthreads();

  for(int ins=0; ins<NINS; ++ins){
    const int l1=c_L1[ins], l2=c_L2[ins], l3=c_L3[ins];
    const int d1=2*l1+1, d2=2*l2+1, d3=2*l3+1;
    const float* w3=w3j+c_W3OFF[ins];
    const int xo=xoff(l1), so=shoff(l2);
    // B1: shw[e][i*d3+k] = sum_j w3j[i,j,k]*sh[e,j]
    const int n1=TILE_E*d1*d3;
    for(int idx=t; idx<n1; idx+=256){
      int e=idx/(d1*d3), r=idx-e*(d1*d3);
      int i=r/d3, k=r-i*d3;
      float s=0.f;
      for(int j=0;j<d2;++j) s += w3[(i*d2+j)*d3+k]*shl[e][so+j];
      shw[e][r]=s;
    }
    __syncthreads();
    // B2: y[e][u*d3+k] = sum_i shw[e][i*d3+k] * x[src[e], xo+u*d1+i]
    const int n2=TILE_E*32*d3;
    for(int idx=t; idx<n2; idx+=256){
      int e=idx/(32*d3), r=idx-e*(32*d3);
      int u=r/d3, k=r-u*d3;
      float s=0.f;
      int srn=srcs[e];
      if(srn>=0){
        const float* xr=x+(size_t)srn*IND+xo+u*d1;
        for(int i=0;i<d1;++i) s += shw[e][i*d3+k]*xr[i];
      }
      ybuf[e][r]=s;
    }
    __syncthreads();
    const float pw=(l3==0)?pwc0:((l3==1)?pwc1:pwc2);
    const int oo=xoff(l3);
    const float* w2b=W2+ins*1024;
    for(int uc=0; uc<32/UCH; ++uc){
      { // wi[e][up][w] = sum_c h[e][c]*W2[c, ins*1024+(uc*8+up)*32+w]
        const int col=uc*256+t;           // up=t>>5, w=t&31
        const float* wp=w2b+col;
        float acc[TILE_E];
        #pragma unroll
        for(int e=0;e<TILE_E;++e) acc[e]=0.f;
        #pragma unroll 2
        for(int c=0;c<64;++c){
          float w2v=wp[(size_t)c*W2N];
          const float4* h4=(const float4*)&hs_t[c*TILE_E];
          float4 a0=h4[0], a1=h4[1], a2=h4[2], a3=h4[3];
          acc[0] += a0.x*w2v; acc[1] += a0.y*w2v; acc[2] += a0.z*w2v; acc[3] += a0.w*w2v;
          acc[4] += a1.x*w2v; acc[5] += a1.y*w2v; acc[6] += a1.z*w2v; acc[7] += a1.w*w2v;
          acc[8] += a2.x*w2v; acc[9] += a2.y*w2v; acc[10]+= a2.z*w2v; acc[11]+= a2.w*w2v;
          acc[12]+= a3.x*w2v; acc[13]+= a3.y*w2v; acc[14]+= a3.z*w2v; acc[15]+= a3.w*w2v;
        }
        const int up=t>>5, w=t&31;
        #pragma unroll
        for(int e=0;e<TILE_E;++e) wi[e][up][w]=acc[e];
      }
      __syncthreads();
      // contract: msg[e][oo+w*d3+k] += pw * sum_up wi[e][up][w]*y[e][(uc*8+up)*d3+k]
      const int n3=TILE_E*32*d3;
      for(int idx=t; idx<n3; idx+=256){
        int e=idx/(32*d3), r=idx-e*(32*d3);
        int w=r/d3, k=r-w*d3;
        float s=0.f;
        #pragma unroll
        for(int up=0; up<UCH; ++up)
          s += wi[e][up][w]*ybuf[e][(uc*UCH+up)*d3+k];
        msg[e][oo+w*d3+k] += pw*s;
      }
      __syncthreads();
    }
  }
  // scatter to out[dst]
  for(int idx=t; idx<TILE_E*IND; idx+=256){
    int e=idx/IND, o=idx-e*IND;
    int d=dsts[e];
    if(d>=0) atomicAdd(&out[(size_t)d*IND+o], msg[e][o]);
  }
}

extern "C" void kernel_launch(void* const* d_in, const int* in_sizes, int n_in,
                              void* d_out, int out_size, void* d_ws, size_t ws_size,
                              hipStream_t stream){
  const float* x     =(const float*)d_in[0];
  const int*   eidx  =(const int*)  d_in[1];
  const float* sh    =(const float*)d_in[2];
  const float* radial=(const float*)d_in[3];
  const float* W1    =(const float*)d_in[4];
  const float* W2    =(const float*)d_in[5];
  const float* Wsc0  =(const float*)d_in[6];
  const float* Wsc1  =(const float*)d_in[7];
  const float* Wsc2  =(const float*)d_in[8];
  float* out=(float*)d_out;
  int n_nodes=in_sizes[0]/IND;
  int E=in_sizes[1]/2;

  float inv10=1.0f/sqrtf(10.0f);
  // PW[l]=sqrt((2l+1)/(n_paths*32)); fold in W2's 1/sqrt(64) and 1/sqrt(NUM_NEIGHBORS)
  float pwc0=sqrtf(1.0f/96.0f) *0.125f*inv10;
  float pwc1=sqrtf(3.0f/128.0f)*0.125f*inv10;
  float pwc2=sqrtf(5.0f/128.0f)*0.125f*inv10;
  float silu_cst=1.67682f;   // 1/sqrt(E[silu(N(0,1))^2]), analytic

  float* w3j=(float*)d_ws;   // 363 floats

  hipLaunchKernelGGL(w3j_kernel, dim3(NINS), dim3(128), 0, stream, w3j);
  hipLaunchKernelGGL(sc_kernel, dim3(n_nodes), dim3(256), 0, stream,
                     x, Wsc0, Wsc1, Wsc2, out, n_nodes);
  hipLaunchKernelGGL(tp_kernel, dim3((E+TILE_E-1)/TILE_E), dim3(256), 0, stream,
                     x, eidx, sh, radial, W1, W2, w3j, out, E,
                     pwc0, pwc1, pwc2, silu_cst);
}

// Round 3
// 300.070 us; speedup vs baseline: 12.7916x; 3.6768x over previous
//
#include <hip/hip_runtime.h>
#include <math.h>

#define TILE_E 16
#define NINS 11
#define IND 288
#define SHD 9
#define W2N 11264

typedef _Float16 half8 __attribute__((ext_vector_type(8)));
typedef float f32x4 __attribute__((ext_vector_type(4)));

__device__ const int c_L1[NINS] = {0,0,0,1,1,1,1,2,2,2,2};
__device__ const int c_L2[NINS] = {0,1,2,0,1,1,2,0,1,2,2};
__device__ const int c_L3[NINS] = {0,1,2,1,0,2,1,2,1,0,2};
__device__ const int c_W3OFF[NINS] = {0,1,10,35,44,53,98,143,168,213,238};

__device__ __forceinline__ int xoff(int l){ return l==0?0:(l==1?32:128); }
__device__ __forceinline__ int shoff(int l){ return l==0?0:(l==1?1:4); }

// ---------------- Wigner 3j on device (exact port of reference, parallel) ----------------
__device__ double dfac(int n){ double r=1.0; for(int i=2;i<=n;++i) r*=(double)i; return r; }

__device__ void qmat_dev(int l,double* qr,double* qi){
  int d=2*l+1;
  for(int i=0;i<d*d;++i){qr[i]=0.0;qi[i]=0.0;}
  const double s=0.70710678118654752440;
  for(int m=-l;m<0;++m){
    qr[(l+m)*d+(l-m)]=s;
    qi[(l+m)*d+(l+m)]=-s;
  }
  qr[l*d+l]=1.0;
  for(int m=1;m<=l;++m){
    double sg=(m&1)?-1.0:1.0;
    qr[(l+m)*d+(l+m)]=sg*s;
    qi[(l+m)*d+(l-m)]=sg*s;
  }
  if(l==1){ for(int i=0;i<d*d;++i){ double a=qr[i],b=qi[i]; qr[i]=b; qi[i]=-a; } }
  else if(l==2){ for(int i=0;i<d*d;++i){ qr[i]=-qr[i]; qi[i]=-qi[i]; } }
}

__global__ __launch_bounds__(128) void w3j_kernel(float* w3j){
  const int ins=blockIdx.x;
  const int l1=c_L1[ins],l2=c_L2[ins],l3=c_L3[ins];
  const int d1=2*l1+1,d2=2*l2+1,d3=2*l3+1;
  const int n=d1*d2*d3;
  const int t=threadIdx.x;

  __shared__ double C[125];
  __shared__ double R[125];
  __shared__ double q1r[25],q1i[25],q2r[25],q2i[25],q3r[25],q3i[25];
  __shared__ double inv;

  for(int i=t;i<125;i+=128) C[i]=0.0;
  if(t==0){
    qmat_dev(l1,q1r,q1i); qmat_dev(l2,q2r,q2i); qmat_dev(l3,q3r,q3i);
  }
  __syncthreads();

  if(t<d1*d2){
    int m1=t/d2-l1, m2=t-(t/d2)*d2-l2;
    int m3=m1+m2;
    if(m3>=-l3 && m3<=l3){
      int vmin=-l1+l2+m3; if(-l1+m1>vmin)vmin=-l1+m1; if(0>vmin)vmin=0;
      int vmax=l2+l3+m1; if(l3-l1+l2<vmax)vmax=l3-l1+l2; if(l3+m3<vmax)vmax=l3+m3;
      double c=sqrt((double)(2*l3+1)*dfac(l3+l1-l2)*dfac(l3-l1+l2)*dfac(l1+l2-l3)
        *dfac(l3+m3)*dfac(l3-m3)
        /(dfac(l1+l2+l3+1)*dfac(l1-m1)*dfac(l1+m1)*dfac(l2-m2)*dfac(l2+m2)));
      double s=0.0;
      for(int v=vmin;v<=vmax;++v){
        double term=dfac(l2+l3+m1-v)*dfac(l1-m1+v)
          /(dfac(v)*dfac(l3-l1+l2-v)*dfac(l3+m3-v)*dfac(v+l1-l2-m3));
        s += (((v+l2+m2)&1)?-1.0:1.0)*term;
      }
      C[((m1+l1)*d2+(m2+l2))*d3+(m3+l3)]=c*s;
    }
  }
  __syncthreads();

  if(t<n){
    int j=t/(d2*d3);
    int rem=t-j*(d2*d3);
    int l=rem/d3, m=rem-l*d3;
    double sr=0.0;
    for(int a=0;a<d1;++a)for(int b=0;b<d2;++b)for(int nn=0;nn<d3;++nn){
      double cv=C[(a*d2+b)*d3+nn];
      if(cv==0.0) continue;
      double xr=q1r[a*d1+j],xi=q1i[a*d1+j];
      double yr=q2r[b*d2+l],yi=q2i[b*d2+l];
      double zr=q3r[nn*d3+m],zi=-q3i[nn*d3+m];
      double pr=xr*yr-xi*yi, pi=xr*yi+xi*yr;
      sr += (pr*zr-pi*zi)*cv;
    }
    R[t]=sr;
  }
  __syncthreads();
  if(t==0){
    double n2=0.0;
    for(int i=0;i<n;++i) n2+=R[i]*R[i];
    inv=1.0/sqrt(n2);
  }
  __syncthreads();
  if(t<n) w3j[c_W3OFF[ins]+t]=(float)(R[t]*inv);
}

// ---------------- pack W2 into f16 MFMA A-fragment order ----------------
// A-fragment for tile t (16 cols), kstep s: lane l elem i holds
//   W2[s*32 + (l>>4)*8 + i][t*16 + (l&15)]
// stored at w2h[((t*2+s)*64 + l)*8 + i]
__global__ __launch_bounds__(256) void pack_w2(const float* __restrict__ W2,
                                               _Float16* __restrict__ w2h){
  int q = blockIdx.x*256 + threadIdx.x;      // (t,s,l) id; 704*2*64 = 90112
  if(q >= 704*2*64) return;
  int l = q & 63;
  int s = (q>>6)&1;
  int t = q>>7;
  int col = t*16 + (l&15);
  int c0  = s*32 + ((l>>4)<<3);
  half8 v;
  #pragma unroll
  for(int i=0;i<8;++i) v[i] = (_Float16)W2[(size_t)(c0+i)*W2N + col];
  *(half8*)&w2h[(size_t)q*8] = v;
}

// ---------------- self connection: out[n] = o3.Linear(x[n]) ----------------
__global__ __launch_bounds__(256) void sc_kernel(const float* __restrict__ x,
  const float* __restrict__ W0, const float* __restrict__ W1s, const float* __restrict__ W2s,
  float* __restrict__ out, int n_nodes)
{
  int n=blockIdx.x;
  if(n>=n_nodes) return;
  const float inv=0.17677669529663689f;  // 1/sqrt(32)
  for(int o=threadIdx.x; o<IND; o+=blockDim.x){
    const float* W; int w,k,d,xo;
    if(o<32){W=W0; w=o; k=0; d=1; xo=0;}
    else if(o<128){int r=o-32; W=W1s; d=3; w=r/3; k=r-w*3; xo=32;}
    else {int r=o-128; W=W2s; d=5; w=r/5; k=r-w*5; xo=128;}
    float s=0.f;
    const float* xr=x+(size_t)n*IND+xo+k;
    for(int u=0;u<32;++u) s += xr[u*d]*W[u*32+w];
    out[(size_t)n*IND+o]=s*inv;
  }
}

// ---------------- contract phase (templated on d3: kills runtime int-div) ----------------
template<int D3>
__device__ __forceinline__ void contract_uc(
    const float (*wi)[260], const float (*ybuf)[160], float (*msg)[IND],
    int t, int uc, int oo, float pw)
{
  const int n3 = TILE_E*32*D3;
  for(int idx=t; idx<n3; idx+=256){
    int e = idx/(32*D3), r = idx - e*(32*D3);
    int w = r/D3, k = r - w*D3;
    float s = 0.f;
    #pragma unroll
    for(int up=0; up<8; ++up)
      s += wi[e][up*32+w] * ybuf[e][(uc*8+up)*D3+k];
    msg[e][oo + w*D3 + k] += pw*s;
  }
}

// ---------------- fused weight-NN + MFMA tensor product + scatter ----------------
__global__ __launch_bounds__(256) void tp_kernel(
    const float* __restrict__ x, const int* __restrict__ eidx,
    const float* __restrict__ sh, const float* __restrict__ radial,
    const float* __restrict__ W1, const _Float16* __restrict__ w2h,
    const float* __restrict__ w3j, float* __restrict__ out,
    int E, float pwc0, float pwc1, float pwc2, float silu_cst)
{
  __shared__ _Float16 h16[TILE_E][64];     // h as f16, row-major per edge
  __shared__ float shl[TILE_E][SHD];
  __shared__ float shw[TILE_E][25];
  __shared__ float ybuf[TILE_E][160];
  __shared__ float wi_lds[TILE_E][260];    // pad 260: 2-way (free) bank alias on b128 stores
  __shared__ float msg[TILE_E][IND];
  __shared__ int srcs[TILE_E];
  __shared__ int dsts[TILE_E];

  const int t=threadIdx.x;
  const int e0=blockIdx.x*TILE_E;

  if(t<TILE_E){
    int eg=e0+t;
    srcs[t]= (eg<E)? eidx[eg] : -1;
    dsts[t]= (eg<E)? eidx[E+eg] : -1;
  }
  // h = SILU_CST * silu(radial @ W1 / 8)  -> f16
  for(int idx=t; idx<TILE_E*64; idx+=256){
    int e=idx>>6, c=idx&63;
    int eg=e0+e;
    float hv=0.f;
    if(eg<E){
      const float* rr=radial+(size_t)eg*64;
      float acc=0.f;
      #pragma unroll 8
      for(int r=0;r<64;++r) acc += rr[r]*W1[r*64+c];
      acc*=0.125f;
      hv=silu_cst*acc/(1.f+expf(-acc));
    }
    h16[e][c]=(_Float16)hv;
  }
  for(int idx=t; idx<TILE_E*SHD; idx+=256){
    int e=idx/SHD, j=idx-e*SHD;
    int eg=e0+e;
    shl[e][j]= (eg<E)? sh[(size_t)eg*SHD+j] : 0.f;
  }
  for(int idx=t; idx<TILE_E*IND; idx+=256) msg[idx/IND][idx-(idx/IND)*IND]=0.f;
  __syncthreads();

  const int wv=t>>6, ln=t&63;
  const int eA=ln&15, gA=ln>>4;

  // B fragments (h), reused for all 44 (ins,uc) passes:
  // lane l holds B[k=(l>>4)*8+i][n=e=l&15] = h[e][s*32+(l>>4)*8+i]
  half8 hb0 = *(const half8*)&h16[eA][gA*8];
  half8 hb1 = *(const half8*)&h16[eA][32+gA*8];

  const half8* w2p=(const half8*)w2h;
  auto LD=[&](int tg,int q,int s)->half8{ return w2p[(size_t)(((tg+q)*2+s)*64+ln)]; };

  // prefetch A-fragments for ii=0 (ins=0, uc=0): global tile = ins*64+uc*16+wv*4+q
  int tg0 = wv*4;
  half8 a00=LD(tg0,0,0), a01=LD(tg0,0,1);
  half8 a10=LD(tg0,1,0), a11=LD(tg0,1,1);
  half8 a20=LD(tg0,2,0), a21=LD(tg0,2,1);
  half8 a30=LD(tg0,3,0), a31=LD(tg0,3,1);

  for(int ii=0; ii<44; ++ii){
    const int ins=ii>>2, uc=ii&3;
    const int l1=c_L1[ins], l2=c_L2[ins], l3=c_L3[ins];
    const int d1=2*l1+1, d2=2*l2+1, d3=2*l3+1;

    if(uc==0){
      const float* w3=w3j+c_W3OFF[ins];
      const int so=shoff(l2), xo=xoff(l1);
      // B1: shw[e][i*d3+k] = sum_j w3j[i,j,k]*sh[e,j]
      const int dd=d1*d3;
      const int n1=TILE_E*dd;
      for(int idx=t; idx<n1; idx+=256){
        int e=idx/dd, r=idx-e*dd;
        int i=r/d3, k=r-i*d3;
        float s=0.f;
        for(int j=0;j<d2;++j) s += w3[(i*d2+j)*d3+k]*shl[e][so+j];
        shw[e][r]=s;
      }
      __syncthreads();
      // B2: ybuf[e][u*d3+k] = sum_i shw[e][i*d3+k] * x[src[e], xo+u*d1+i]
      const int n2=TILE_E*32*d3;
      for(int idx=t; idx<n2; idx+=256){
        int e=idx/(32*d3), r=idx-e*(32*d3);
        int u=r/d3, k=r-u*d3;
        float s=0.f;
        int srn=srcs[e];
        if(srn>=0){
          const float* xr=x+(size_t)srn*IND+xo+u*d1;
          for(int i=0;i<d1;++i) s += shw[e][i*d3+k]*xr[i];
        }
        ybuf[e][r]=s;
      }
      __syncthreads();
    }

    // issue prefetch for next pass (hidden under MFMA + contract)
    int jn = (ii+1<44)? ii+1 : ii;
    int tgn = (jn>>2)*64 + (jn&3)*16 + wv*4;
    half8 n00=LD(tgn,0,0), n01=LD(tgn,0,1);
    half8 n10=LD(tgn,1,0), n11=LD(tgn,1,1);
    half8 n20=LD(tgn,2,0), n21=LD(tgn,2,1);
    half8 n30=LD(tgn,3,0), n31=LD(tgn,3,1);

    // MFMA: wi[e][c] = sum_c64 h[e][c64]*W2[c64][ins*1024+uc*256+c]
    // D lane map (verified): n(col)=lane&15 -> e ; m(row)=(lane>>4)*4+j -> local col
    {
      f32x4 z; z[0]=0.f; z[1]=0.f; z[2]=0.f; z[3]=0.f;
      f32x4 acc0=__builtin_amdgcn_mfma_f32_16x16x32_f16(a00,hb0,z,0,0,0);
      acc0      =__builtin_amdgcn_mfma_f32_16x16x32_f16(a01,hb1,acc0,0,0,0);
      f32x4 acc1=__builtin_amdgcn_mfma_f32_16x16x32_f16(a10,hb0,z,0,0,0);
      acc1      =__builtin_amdgcn_mfma_f32_16x16x32_f16(a11,hb1,acc1,0,0,0);
      f32x4 acc2=__builtin_amdgcn_mfma_f32_16x16x32_f16(a20,hb0,z,0,0,0);
      acc2      =__builtin_amdgcn_mfma_f32_16x16x32_f16(a21,hb1,acc2,0,0,0);
      f32x4 acc3=__builtin_amdgcn_mfma_f32_16x16x32_f16(a30,hb0,z,0,0,0);
      acc3      =__builtin_amdgcn_mfma_f32_16x16x32_f16(a31,hb1,acc3,0,0,0);
      const int cb=gA*4;
      *(f32x4*)&wi_lds[eA][(wv*4+0)*16+cb]=acc0;
      *(f32x4*)&wi_lds[eA][(wv*4+1)*16+cb]=acc1;
      *(f32x4*)&wi_lds[eA][(wv*4+2)*16+cb]=acc2;
      *(f32x4*)&wi_lds[eA][(wv*4+3)*16+cb]=acc3;
    }
    __syncthreads();

    const float pw=(l3==0)?pwc0:((l3==1)?pwc1:pwc2);
    const int oo=xoff(l3);
    if(l3==0)      contract_uc<1>(wi_lds,ybuf,msg,t,uc,oo,pw);
    else if(l3==1) contract_uc<3>(wi_lds,ybuf,msg,t,uc,oo,pw);
    else           contract_uc<5>(wi_lds,ybuf,msg,t,uc,oo,pw);
    __syncthreads();

    a00=n00; a01=n01; a10=n10; a11=n11;
    a20=n20; a21=n21; a30=n30; a31=n31;
  }

  // scatter to out[dst]
  for(int idx=t; idx<TILE_E*IND; idx+=256){
    int e=idx/IND, o=idx-e*IND;
    int d=dsts[e];
    if(d>=0) atomicAdd(&out[(size_t)d*IND+o], msg[e][o]);
  }
}

extern "C" void kernel_launch(void* const* d_in, const int* in_sizes, int n_in,
                              void* d_out, int out_size, void* d_ws, size_t ws_size,
                              hipStream_t stream){
  const float* x     =(const float*)d_in[0];
  const int*   eidx  =(const int*)  d_in[1];
  const float* sh    =(const float*)d_in[2];
  const float* radial=(const float*)d_in[3];
  const float* W1    =(const float*)d_in[4];
  const float* W2    =(const float*)d_in[5];
  const float* Wsc0  =(const float*)d_in[6];
  const float* Wsc1  =(const float*)d_in[7];
  const float* Wsc2  =(const float*)d_in[8];
  float* out=(float*)d_out;
  int n_nodes=in_sizes[0]/IND;
  int E=in_sizes[1]/2;

  float inv10=1.0f/sqrtf(10.0f);
  float pwc0=sqrtf(1.0f/96.0f) *0.125f*inv10;
  float pwc1=sqrtf(3.0f/128.0f)*0.125f*inv10;
  float pwc2=sqrtf(5.0f/128.0f)*0.125f*inv10;
  float silu_cst=1.67682f;

  float* w3j=(float*)d_ws;                                  // 363 floats
  _Float16* w2h=(_Float16*)((char*)d_ws + 2048);            // 720896 f16 = 1.41 MB

  hipLaunchKernelGGL(w3j_kernel, dim3(NINS), dim3(128), 0, stream, w3j);
  hipLaunchKernelGGL(pack_w2, dim3(352), dim3(256), 0, stream, W2, w2h);
  hipLaunchKernelGGL(sc_kernel, dim3(n_nodes), dim3(256), 0, stream,
                     x, Wsc0, Wsc1, Wsc2, out, n_nodes);
  hipLaunchKernelGGL(tp_kernel, dim3((E+TILE_E-1)/TILE_E), dim3(256), 0, stream,
                     x, eidx, sh, radial, W1, w2h, w3j, out, E,
                     pwc0, pwc1, pwc2, silu_cst);
}